// Round 21
// baseline (71.090 us; speedup 1.0000x reference)
//
#include <hip/hip_runtime.h>
#include <hip/hip_bf16.h>
#include <math.h>

#define LOG2E_ 1.4426950408889634f

typedef short short8 __attribute__((ext_vector_type(8)));   // 8 x bf16 (4 VGPRs)
typedef float f32x4 __attribute__((ext_vector_type(4)));
typedef int int4v __attribute__((ext_vector_type(4)));

#if defined(__has_builtin)
#if __has_builtin(__builtin_amdgcn_exp2f)
#define EXP2F(x) __builtin_amdgcn_exp2f(x)
#else
#define EXP2F(x) exp2f(x)
#endif
#else
#define EXP2F(x) exp2f(x)
#endif

static __device__ __forceinline__ unsigned short f2bf(float f) {
    union { float f; unsigned int u; } c; c.f = f;
    c.u += 0x7fffu + ((c.u >> 16) & 1u);      // RNE (no NaN inputs here)
    return (unsigned short)(c.u >> 16);
}
static __device__ __forceinline__ int pk2bf(float a, float b) {
    union { __hip_bfloat162 h; int i; } u;
    u.h = __float22bfloat162_rn(make_float2(a, b));   // x -> low 16 bits
    return u.i;
}
// async 16B global -> LDS (wave-uniform LDS base + lane*16; per-lane global src)
static __device__ __forceinline__ void load_lds16(const void* g, void* l) {
    __builtin_amdgcn_global_load_lds(
        (const __attribute__((address_space(1))) void*)g,
        (__attribute__((address_space(3))) void*)l, 16, 0, 0);
}

// ---------------------------------------------------------------------------
// Fused LN + tri (f32 tiled, log2e-scaled) + per-head pre-swizzled weight
// images. blocks 0..8191: LN. blocks 8192..8233: wimg[4][43008]:
//   bytes 0..32767  : 4 slices (q,k,v,g) of 8192B, XOR-swizzled rows
//   bytes 32768..43007: Wo slice, pitch 80 (64B data + 16B pad)
// triT[h][qt][kt][m][kc] : off = h*65536 + qt*4096 + kt*256 + m*16 + kc  (f32)
// ---------------------------------------------------------------------------
__global__ __launch_bounds__(256) void ln_prep_kernel(
    const float* __restrict__ x, const float* __restrict__ ln_w,
    const float* __restrict__ ln_b, const float* __restrict__ tri_w,
    const float* __restrict__ qw, const float* __restrict__ kw,
    const float* __restrict__ vw, const float* __restrict__ gw,
    const float* __restrict__ ow,
    unsigned short* __restrict__ xn, float* __restrict__ triT,
    char* __restrict__ wimg)
{
    const int bid = blockIdx.x, tid = threadIdx.x;
    if (bid >= 8192) {
        int id = (bid - 8192) * 256 + tid;        // 0 .. 10751
        int h = id / 2688;
        int b = (id - h * 2688) * 16;             // byte offset in head image
        unsigned short v[8];
        if (b < 32768) {
            int sl = b >> 13;
            int bi = b & 8191;
            int row = bi >> 8;
            int c8 = ((bi >> 4) & 15) ^ (row & 7);
            const float* src = (sl == 0) ? qw : (sl == 1) ? kw : (sl == 2) ? vw : gw;
            float scale = (sl == 0) ? (0.17677669529663687f * LOG2E_) : 1.0f;
            int R = h * 32 + row;
            #pragma unroll
            for (int e = 0; e < 8; ++e)
                v[e] = f2bf(src[(c8 * 8 + e) * 128 + R] * scale);
        } else {
            int o = b - 32768;
            int n = o / 80;
            int k8 = (o - n * 80) >> 4;
            if (k8 < 4) {
                #pragma unroll
                for (int e = 0; e < 8; ++e)
                    v[e] = f2bf(ow[(h * 32 + k8 * 8 + e) * 128 + n]);
            } else {
                #pragma unroll
                for (int e = 0; e < 8; ++e) v[e] = 0;   // pad bytes 64..79
            }
        }
        *(short8*)(wimg + h * 43008 + b) = *(short8*)v;
        return;
    }

    const int row = bid * 8 + (tid >> 5);
    const int l = tid & 31;

    float4 xv = *(const float4*)(x + (size_t)row * 128 + l * 4);
    float s = (xv.x + xv.y) + (xv.z + xv.w);
    #pragma unroll
    for (int mk = 16; mk >= 1; mk >>= 1) s += __shfl_xor(s, mk, 64);
    float mu = s * (1.0f / 128.0f);

    float d0 = xv.x - mu, d1 = xv.y - mu, d2 = xv.z - mu, d3 = xv.w - mu;
    float sq = (d0 * d0 + d1 * d1) + (d2 * d2 + d3 * d3);
    #pragma unroll
    for (int mk = 16; mk >= 1; mk >>= 1) sq += __shfl_xor(sq, mk, 64);
    float rstd = rsqrtf(sq * (1.0f / 128.0f) + 1e-5f);

    float4 wv = *(const float4*)(ln_w + l * 4);
    float4 bv = *(const float4*)(ln_b + l * 4);
    float n0 = d0 * rstd * wv.x + bv.x;
    float n1 = d1 * rstd * wv.y + bv.y;
    float n2 = d2 * rstd * wv.z + bv.z;
    float n3 = d3 * rstd * wv.w + bv.w;

    ushort4 xo;
    xo.x = f2bf(n0); xo.y = f2bf(n1); xo.z = f2bf(n2); xo.w = f2bf(n3);
    *(ushort4*)(xn + (size_t)row * 128 + l * 4) = xo;

    float4 t0 = *(const float4*)(tri_w + (l * 4 + 0) * 4);
    float4 t1 = *(const float4*)(tri_w + (l * 4 + 1) * 4);
    float4 t2 = *(const float4*)(tri_w + (l * 4 + 2) * 4);
    float4 t3 = *(const float4*)(tri_w + (l * 4 + 3) * 4);
    float ax = (n0 * t0.x + n1 * t1.x) + (n2 * t2.x + n3 * t3.x);
    float ay = (n0 * t0.y + n1 * t1.y) + (n2 * t2.y + n3 * t3.y);
    float az = (n0 * t0.z + n1 * t1.z) + (n2 * t2.z + n3 * t3.z);
    float aw = (n0 * t0.w + n1 * t1.w) + (n2 * t2.w + n3 * t3.w);
    #pragma unroll
    for (int mk = 16; mk >= 1; mk >>= 1) {
        ax += __shfl_xor(ax, mk, 64);
        ay += __shfl_xor(ay, mk, 64);
        az += __shfl_xor(az, mk, 64);
        aw += __shfl_xor(aw, mk, 64);
    }
    if (l < 4) {
        float v = (l == 0) ? ax : (l == 1) ? ay : (l == 2) ? az : aw;
        int q = row >> 8, kc = row & 255;
        int off = l * 65536 + (q >> 4) * 4096 + (kc >> 4) * 256
                + (q & 15) * 16 + (kc & 15);
        triT[off] = v * LOG2E_;
    }
}

// ---------------------------------------------------------------------------
// Mega kernel: 256 blocks x 1024 threads (16 waves = 4/SIMD, 1 block/CU).
// Round-16/20 configuration + merged QK setprio bracket: both kt sub-chunks'
// K fragments and biases issued up front, both QK MFMAs back-to-back in ONE
// setprio cluster (removes the scheduler fence between two independent
// MFMAs; their exp chains overlap). Register-level only.
// ---------------------------------------------------------------------------
__global__ __launch_bounds__(1024, 4) void mega_kernel(
    const unsigned short* __restrict__ xn, const char* __restrict__ wimg,
    const float* __restrict__ g_b, const float* __restrict__ mask,
    const float* __restrict__ triT, const float* __restrict__ o_b,
    float* __restrict__ out)
{
    __shared__ __align__(16) char WBUF[2 * 43008];         // qkvg 4x8KB + wo 10KB
    __shared__ __align__(16) unsigned short Qg[256 * 36];  // Q then OG (18KB)
    __shared__ __align__(16) unsigned short Kl[256 * 36];  // 18KB
    __shared__ __align__(16) unsigned short Vc[32 * 264];  // col-major V, pad 264
    __shared__ float mb[256];

    const int i = blockIdx.x;
    const int tid = threadIdx.x;
    const int w = tid >> 6, lane = tid & 63, g = lane >> 4, m = lane & 15;
    const f32x4 zero = {0.f, 0.f, 0.f, 0.f};

    // ---- X fragments in registers: this wave's 16 rows
    short8 xa[4];
    #pragma unroll
    for (int kc = 0; kc < 4; ++kc)
        xa[kc] = *(const short8*)(xn + (size_t)(i * 256 + w * 16 + m) * 128
                                  + kc * 32 + 8 * g);
    if (tid < 256) mb[tid] = (mask[i * 256 + tid] - 1.0f) * (1.0e9f * LOG2E_);

    // ---- async stage of head-0 weights
    {
        const char* src = wimg + w * 1024 + lane * 16;
        char* dst = WBUF + w * 1024;
        load_lds16(src, dst);
        load_lds16(src + 16384, dst + 16384);
        if (w < 10) load_lds16(src + 32768, dst + 32768);
    }
    __syncthreads();   // drains vmcnt (incl. load_lds) + cross-wave sync

    // bpermute exchange constants
    const int srcA = ((g & 1) << 1) | (g >> 1);
    const int idxA = (srcA * 16 + m) * 4;
    const int idxB = idxA ^ 64;
    const bool low = (lane < 32);
    const bool odd = (g & 1);
    const char* VcB0 = (const char*)Vc + m * 528;
    const char* VcB1 = (const char*)Vc + (16 + m) * 528;

    f32x4 oacc[8];
    #pragma unroll
    for (int nt = 0; nt < 8; ++nt) oacc[nt] = zero;

    const int qrow = w * 16 + m;

    #pragma unroll 1
    for (int h = 0; h < 4; ++h) {
        const char* wb = WBUF + (h & 1) * 43008;

        // ===== proj pass A: Q and K =====
        {
            f32x4 aq[2] = {zero, zero}, ak[2] = {zero, zero};
            #pragma unroll
            for (int kc = 0; kc < 4; ++kc) {
                short8 b0[2], b1[2];
                #pragma unroll
                for (int nt = 0; nt < 2; ++nt) {
                    int row = nt * 16 + m;
                    int off = (row * 256 + kc * 64 + 16 * g) ^ ((row & 7) << 4);
                    b0[nt] = *(const short8*)(wb + off);
                    b1[nt] = *(const short8*)(wb + 8192 + off);
                }
                __builtin_amdgcn_s_setprio(1);
                #pragma unroll
                for (int nt = 0; nt < 2; ++nt) {
                    aq[nt] = __builtin_amdgcn_mfma_f32_16x16x32_bf16(b0[nt], xa[kc], aq[nt], 0, 0, 0);
                    ak[nt] = __builtin_amdgcn_mfma_f32_16x16x32_bf16(b1[nt], xa[kc], ak[nt], 0, 0, 0);
                }
                __builtin_amdgcn_s_setprio(0);
            }
            #pragma unroll
            for (int nt = 0; nt < 2; ++nt) {
                int col = nt * 16 + 4 * g;
                ushort4 q4, k4;
                q4.x = f2bf(aq[nt][0]); q4.y = f2bf(aq[nt][1]);
                q4.z = f2bf(aq[nt][2]); q4.w = f2bf(aq[nt][3]);
                k4.x = f2bf(ak[nt][0]); k4.y = f2bf(ak[nt][1]);
                k4.z = f2bf(ak[nt][2]); k4.w = f2bf(ak[nt][3]);
                *(ushort4*)(Qg + qrow * 36 + col) = q4;
                *(ushort4*)(Kl + qrow * 36 + col) = k4;
            }
        }

        // ===== proj pass B: V (normal order -> vector col-major store) and
        //       G (swapped order, gate -> accumulator regs) =====
        f32x4 gacc[2];
        {
            f32x4 av4[2] = {zero, zero}, ag[2] = {zero, zero};
            #pragma unroll
            for (int kc = 0; kc < 4; ++kc) {
                short8 b0[2], b1[2];
                #pragma unroll
                for (int nt = 0; nt < 2; ++nt) {
                    int row = nt * 16 + m;
                    int off = (row * 256 + kc * 64 + 16 * g) ^ ((row & 7) << 4);
                    b0[nt] = *(const short8*)(wb + 16384 + off);
                    b1[nt] = *(const short8*)(wb + 24576 + off);
                }
                __builtin_amdgcn_s_setprio(1);
                #pragma unroll
                for (int nt = 0; nt < 2; ++nt) {
                    // V: NORMAL order -> lane (g,m) holds V[k=w*16+4g+r][d=nt*16+m]
                    av4[nt] = __builtin_amdgcn_mfma_f32_16x16x32_bf16(xa[kc], b0[nt], av4[nt], 0, 0, 0);
                    // G: swapped order (matches OG-store layout)
                    ag[nt]  = __builtin_amdgcn_mfma_f32_16x16x32_bf16(b1[nt], xa[kc], ag[nt], 0, 0, 0);
                }
                __builtin_amdgcn_s_setprio(0);
            }
            #pragma unroll
            for (int nt = 0; nt < 2; ++nt) {
                // Vc[d][k]: 4 consecutive k at fixed d -> one ushort4 store
                ushort4 v4;
                v4.x = f2bf(av4[nt][0]); v4.y = f2bf(av4[nt][1]);
                v4.z = f2bf(av4[nt][2]); v4.w = f2bf(av4[nt][3]);
                *(ushort4*)(Vc + (nt * 16 + m) * 264 + w * 16 + 4 * g) = v4;
                int col = nt * 16 + 4 * g;
                #pragma unroll
                for (int r = 0; r < 4; ++r)
                    gacc[nt][r] = 1.0f / (1.0f + __expf(-(ag[nt][r] + g_b[h * 32 + col + r])));
            }
        }
        __syncthreads();   // proj writes -> attn reads

        // ===== async stage of head h+1 (lands during attention) =====
        if (h < 3) {
            const char* src = wimg + (h + 1) * 43008 + w * 1024 + lane * 16;
            char* dst = WBUF + ((h + 1) & 1) * 43008 + w * 1024;
            load_lds16(src, dst);
            load_lds16(src + 16384, dst + 16384);
            if (w < 10) load_lds16(src + 32768, dst + 32768);
        }

        // ===== attention: this wave's q-tile =====
        const short8 qf = *(const short8*)((const char*)Qg + qrow * 72 + 16 * g);
        const float* triQ = triT + h * 65536 + w * 4096 + m * 16 + 4 * g;

        float ls = 0.f;
        f32x4 o0 = zero, o1 = zero;

        #pragma unroll
        for (int c = 0; c < 8; ++c) {
            const int kt0 = 2 * c, kt1 = 2 * c + 1;
            // issue both sub-chunks' operands up front
            short8 af0 = *(const short8*)((const char*)Kl + (kt0 * 16 + m) * 72 + 16 * g);
            short8 af1 = *(const short8*)((const char*)Kl + (kt1 * 16 + m) * 72 + 16 * g);
            f32x4 bias0 = *(const f32x4*)(mb + kt0 * 16 + 4 * g)
                        + *(const f32x4*)(triQ + kt0 * 256);
            f32x4 bias1 = *(const f32x4*)(mb + kt1 * 16 + 4 * g)
                        + *(const f32x4*)(triQ + kt1 * 256);
            // both QK MFMAs back-to-back in one priority cluster
            __builtin_amdgcn_s_setprio(1);
            f32x4 acc0 = __builtin_amdgcn_mfma_f32_16x16x32_bf16(af0, qf, bias0, 0, 0, 0);
            f32x4 acc1 = __builtin_amdgcn_mfma_f32_16x16x32_bf16(af1, qf, bias1, 0, 0, 0);
            __builtin_amdgcn_s_setprio(0);

            float p00 = EXP2F(acc0[0]);
            float p01 = EXP2F(acc0[1]);
            float p02 = EXP2F(acc0[2]);
            float p03 = EXP2F(acc0[3]);
            float p10 = EXP2F(acc1[0]);
            float p11 = EXP2F(acc1[1]);
            float p12 = EXP2F(acc1[2]);
            float p13 = EXP2F(acc1[3]);
            ls += ((p00 + p01) + (p02 + p03)) + ((p10 + p11) + (p12 + p13));
            int d00 = pk2bf(p00, p01), d01 = pk2bf(p02, p03);
            int d10 = pk2bf(p10, p11), d11 = pk2bf(p12, p13);

            // parity relabel (post-MFMA per-lane outputs: legal divergence)
            int pk0 = odd ? d10 : d00;
            int pk1 = odd ? d11 : d01;
            int pk2 = odd ? d00 : d10;
            int pk3 = odd ? d01 : d11;

            int dA0 = __builtin_amdgcn_ds_bpermute(idxA, pk0);
            int dA1 = __builtin_amdgcn_ds_bpermute(idxA, pk1);
            int dB0 = __builtin_amdgcn_ds_bpermute(idxB, pk2);
            int dB1 = __builtin_amdgcn_ds_bpermute(idxB, pk3);
            int4v bi;
            bi.x = low ? dA0 : dB0;
            bi.y = low ? dA1 : dB1;
            bi.z = low ? dB0 : dA0;
            bi.w = low ? dB1 : dA1;
            short8 bs = __builtin_bit_cast(short8, bi);

            short8 av0 = *(const short8*)(VcB0 + c * 64 + 16 * g);
            short8 av1 = *(const short8*)(VcB1 + c * 64 + 16 * g);
            __builtin_amdgcn_s_setprio(1);
            o0 = __builtin_amdgcn_mfma_f32_16x16x32_bf16(av0, bs, o0, 0, 0, 0);
            o1 = __builtin_amdgcn_mfma_f32_16x16x32_bf16(av1, bs, o1, 0, 0, 0);
            __builtin_amdgcn_s_setprio(0);
        }
        ls += __shfl_xor(ls, 16, 64);
        ls += __shfl_xor(ls, 32, 64);
        float inv = 1.0f / ls;

        ushort4 s0, s1;
        s0.x = f2bf(o0[0] * inv * gacc[0][0]);
        s0.y = f2bf(o0[1] * inv * gacc[0][1]);
        s0.z = f2bf(o0[2] * inv * gacc[0][2]);
        s0.w = f2bf(o0[3] * inv * gacc[0][3]);
        s1.x = f2bf(o1[0] * inv * gacc[1][0]);
        s1.y = f2bf(o1[1] * inv * gacc[1][1]);
        s1.z = f2bf(o1[2] * inv * gacc[1][2]);
        s1.w = f2bf(o1[3] * inv * gacc[1][3]);
        *(ushort4*)(Qg + qrow * 36 + 4 * g) = s0;           // OG over Q (own rows)
        *(ushort4*)(Qg + qrow * 36 + 16 + 4 * g) = s1;

        // ===== partial output projection (wave-local rows, no barrier) =====
        {
            short8 a = *(const short8*)((const char*)Qg + qrow * 72 + 16 * g);
            __builtin_amdgcn_s_setprio(1);
            #pragma unroll
            for (int nt = 0; nt < 8; ++nt) {
                short8 b = *(const short8*)(wb + 32768 + (nt * 16 + m) * 80 + 16 * g);
                oacc[nt] = __builtin_amdgcn_mfma_f32_16x16x32_bf16(b, a, oacc[nt], 0, 0, 0);
            }
            __builtin_amdgcn_s_setprio(0);
        }
        __syncthreads();   // drains prefetch vmcnt + all reads done before overwrite
    }

    // ===== epilogue: + o_b, fp32 store =====
    const int orow = i * 256 + qrow;
    #pragma unroll
    for (int nt = 0; nt < 8; ++nt) {
        int col = nt * 16 + 4 * g;
        float4 bv = *(const float4*)(o_b + col);
        float4 o;
        o.x = oacc[nt][0] + bv.x;
        o.y = oacc[nt][1] + bv.y;
        o.z = oacc[nt][2] + bv.z;
        o.w = oacc[nt][3] + bv.w;
        *(float4*)(out + (size_t)orow * 128 + col) = o;
    }
}

// ---------------------------------------------------------------------------
extern "C" void kernel_launch(void* const* d_in, const int* in_sizes, int n_in,
                              void* d_out, int out_size, void* d_ws, size_t ws_size,
                              hipStream_t stream) {
    (void)in_sizes; (void)n_in; (void)out_size; (void)ws_size;
    const float* x    = (const float*)d_in[0];
    const float* mask = (const float*)d_in[1];
    const float* ln_w = (const float*)d_in[2];
    const float* ln_b = (const float*)d_in[3];
    const float* tri_w= (const float*)d_in[4];
    const float* q_w  = (const float*)d_in[5];
    const float* k_w  = (const float*)d_in[6];
    const float* v_w  = (const float*)d_in[7];
    const float* g_w  = (const float*)d_in[8];
    const float* g_b  = (const float*)d_in[9];
    const float* o_w  = (const float*)d_in[10];
    const float* o_b  = (const float*)d_in[11];

    char* ws = (char*)d_ws;
    unsigned short* xn  = (unsigned short*)(ws);                 // 16 MB
    float*          tri = (float*)(ws + 16777216);               // 1 MB f32 tiled
    char*           wimg= (char*)(ws + 17825792);                // 168 KB images

    ln_prep_kernel<<<8234, 256, 0, stream>>>(x, ln_w, ln_b, tri_w,
                                             q_w, k_w, v_w, g_w, o_w,
                                             xn, tri, wimg);
    mega_kernel<<<256, 1024, 0, stream>>>(xn, wimg, g_b, mask, tri, o_b,
                                          (float*)d_out);
}

// Round 22
// 69.669 us; speedup vs baseline: 1.0204x; 1.0204x over previous
//
#include <hip/hip_runtime.h>
#include <hip/hip_bf16.h>
#include <math.h>

#define LOG2E_ 1.4426950408889634f

typedef short short8 __attribute__((ext_vector_type(8)));   // 8 x bf16 (4 VGPRs)
typedef float f32x4 __attribute__((ext_vector_type(4)));
typedef int int4v __attribute__((ext_vector_type(4)));

#if defined(__has_builtin)
#if __has_builtin(__builtin_amdgcn_exp2f)
#define EXP2F(x) __builtin_amdgcn_exp2f(x)
#else
#define EXP2F(x) exp2f(x)
#endif
#else
#define EXP2F(x) exp2f(x)
#endif

static __device__ __forceinline__ unsigned short f2bf(float f) {
    union { float f; unsigned int u; } c; c.f = f;
    c.u += 0x7fffu + ((c.u >> 16) & 1u);      // RNE (no NaN inputs here)
    return (unsigned short)(c.u >> 16);
}
static __device__ __forceinline__ int pk2bf(float a, float b) {
    union { __hip_bfloat162 h; int i; } u;
    u.h = __float22bfloat162_rn(make_float2(a, b));   // x -> low 16 bits
    return u.i;
}
// async 16B global -> LDS (wave-uniform LDS base + lane*16; per-lane global src)
static __device__ __forceinline__ void load_lds16(const void* g, void* l) {
    __builtin_amdgcn_global_load_lds(
        (const __attribute__((address_space(1))) void*)g,
        (__attribute__((address_space(3))) void*)l, 16, 0, 0);
}

// ---------------------------------------------------------------------------
// Fused LN + tri (f32 tiled, log2e-scaled) + per-head pre-swizzled weight
// images. blocks 0..8191: LN. blocks 8192..8233: wimg[4][43008]:
//   bytes 0..32767  : 4 slices (q,k,v,g) of 8192B, XOR-swizzled rows
//   bytes 32768..43007: Wo slice, pitch 80 (64B data + 16B pad)
// triT[h][qt][kt][m][kc] : off = h*65536 + qt*4096 + kt*256 + m*16 + kc  (f32)
// ---------------------------------------------------------------------------
__global__ __launch_bounds__(256) void ln_prep_kernel(
    const float* __restrict__ x, const float* __restrict__ ln_w,
    const float* __restrict__ ln_b, const float* __restrict__ tri_w,
    const float* __restrict__ qw, const float* __restrict__ kw,
    const float* __restrict__ vw, const float* __restrict__ gw,
    const float* __restrict__ ow,
    unsigned short* __restrict__ xn, float* __restrict__ triT,
    char* __restrict__ wimg)
{
    const int bid = blockIdx.x, tid = threadIdx.x;
    if (bid >= 8192) {
        int id = (bid - 8192) * 256 + tid;        // 0 .. 10751
        int h = id / 2688;
        int b = (id - h * 2688) * 16;             // byte offset in head image
        unsigned short v[8];
        if (b < 32768) {
            int sl = b >> 13;
            int bi = b & 8191;
            int row = bi >> 8;
            int c8 = ((bi >> 4) & 15) ^ (row & 7);
            const float* src = (sl == 0) ? qw : (sl == 1) ? kw : (sl == 2) ? vw : gw;
            float scale = (sl == 0) ? (0.17677669529663687f * LOG2E_) : 1.0f;
            int R = h * 32 + row;
            #pragma unroll
            for (int e = 0; e < 8; ++e)
                v[e] = f2bf(src[(c8 * 8 + e) * 128 + R] * scale);
        } else {
            int o = b - 32768;
            int n = o / 80;
            int k8 = (o - n * 80) >> 4;
            if (k8 < 4) {
                #pragma unroll
                for (int e = 0; e < 8; ++e)
                    v[e] = f2bf(ow[(h * 32 + k8 * 8 + e) * 128 + n]);
            } else {
                #pragma unroll
                for (int e = 0; e < 8; ++e) v[e] = 0;   // pad bytes 64..79
            }
        }
        *(short8*)(wimg + h * 43008 + b) = *(short8*)v;
        return;
    }

    const int row = bid * 8 + (tid >> 5);
    const int l = tid & 31;

    float4 xv = *(const float4*)(x + (size_t)row * 128 + l * 4);
    float s = (xv.x + xv.y) + (xv.z + xv.w);
    #pragma unroll
    for (int mk = 16; mk >= 1; mk >>= 1) s += __shfl_xor(s, mk, 64);
    float mu = s * (1.0f / 128.0f);

    float d0 = xv.x - mu, d1 = xv.y - mu, d2 = xv.z - mu, d3 = xv.w - mu;
    float sq = (d0 * d0 + d1 * d1) + (d2 * d2 + d3 * d3);
    #pragma unroll
    for (int mk = 16; mk >= 1; mk >>= 1) sq += __shfl_xor(sq, mk, 64);
    float rstd = rsqrtf(sq * (1.0f / 128.0f) + 1e-5f);

    float4 wv = *(const float4*)(ln_w + l * 4);
    float4 bv = *(const float4*)(ln_b + l * 4);
    float n0 = d0 * rstd * wv.x + bv.x;
    float n1 = d1 * rstd * wv.y + bv.y;
    float n2 = d2 * rstd * wv.z + bv.z;
    float n3 = d3 * rstd * wv.w + bv.w;

    ushort4 xo;
    xo.x = f2bf(n0); xo.y = f2bf(n1); xo.z = f2bf(n2); xo.w = f2bf(n3);
    *(ushort4*)(xn + (size_t)row * 128 + l * 4) = xo;

    float4 t0 = *(const float4*)(tri_w + (l * 4 + 0) * 4);
    float4 t1 = *(const float4*)(tri_w + (l * 4 + 1) * 4);
    float4 t2 = *(const float4*)(tri_w + (l * 4 + 2) * 4);
    float4 t3 = *(const float4*)(tri_w + (l * 4 + 3) * 4);
    float ax = (n0 * t0.x + n1 * t1.x) + (n2 * t2.x + n3 * t3.x);
    float ay = (n0 * t0.y + n1 * t1.y) + (n2 * t2.y + n3 * t3.y);
    float az = (n0 * t0.z + n1 * t1.z) + (n2 * t2.z + n3 * t3.z);
    float aw = (n0 * t0.w + n1 * t1.w) + (n2 * t2.w + n3 * t3.w);
    #pragma unroll
    for (int mk = 16; mk >= 1; mk >>= 1) {
        ax += __shfl_xor(ax, mk, 64);
        ay += __shfl_xor(ay, mk, 64);
        az += __shfl_xor(az, mk, 64);
        aw += __shfl_xor(aw, mk, 64);
    }
    if (l < 4) {
        float v = (l == 0) ? ax : (l == 1) ? ay : (l == 2) ? az : aw;
        int q = row >> 8, kc = row & 255;
        int off = l * 65536 + (q >> 4) * 4096 + (kc >> 4) * 256
                + (q & 15) * 16 + (kc & 15);
        triT[off] = v * LOG2E_;
    }
}

// ---------------------------------------------------------------------------
// Mega kernel: 256 blocks x 1024 threads (16 waves = 4/SIMD, 1 block/CU).
// Round-20 configuration (measured optimum): WBUF double-buffered staging via
// global_load_lds, 2 barriers/head, T5 setprio per MFMA cluster, Kl/Qg pitch
// 72B, Vc pitch 264 (16B-aligned rows). r21's merged-operand variant spilled
// (+16 live VGPRs at peak -> WRITE +12MB); the 64-arch-VGPR budget at 16
// waves/CU admits no wider chunk body.
// ---------------------------------------------------------------------------
__global__ __launch_bounds__(1024, 4) void mega_kernel(
    const unsigned short* __restrict__ xn, const char* __restrict__ wimg,
    const float* __restrict__ g_b, const float* __restrict__ mask,
    const float* __restrict__ triT, const float* __restrict__ o_b,
    float* __restrict__ out)
{
    __shared__ __align__(16) char WBUF[2 * 43008];         // qkvg 4x8KB + wo 10KB
    __shared__ __align__(16) unsigned short Qg[256 * 36];  // Q then OG (18KB)
    __shared__ __align__(16) unsigned short Kl[256 * 36];  // 18KB
    __shared__ __align__(16) unsigned short Vc[32 * 264];  // col-major V, pad 264
    __shared__ float mb[256];

    const int i = blockIdx.x;
    const int tid = threadIdx.x;
    const int w = tid >> 6, lane = tid & 63, g = lane >> 4, m = lane & 15;
    const f32x4 zero = {0.f, 0.f, 0.f, 0.f};

    // ---- X fragments in registers: this wave's 16 rows
    short8 xa[4];
    #pragma unroll
    for (int kc = 0; kc < 4; ++kc)
        xa[kc] = *(const short8*)(xn + (size_t)(i * 256 + w * 16 + m) * 128
                                  + kc * 32 + 8 * g);
    if (tid < 256) mb[tid] = (mask[i * 256 + tid] - 1.0f) * (1.0e9f * LOG2E_);

    // ---- async stage of head-0 weights
    {
        const char* src = wimg + w * 1024 + lane * 16;
        char* dst = WBUF + w * 1024;
        load_lds16(src, dst);
        load_lds16(src + 16384, dst + 16384);
        if (w < 10) load_lds16(src + 32768, dst + 32768);
    }
    __syncthreads();   // drains vmcnt (incl. load_lds) + cross-wave sync

    // bpermute exchange constants
    const int srcA = ((g & 1) << 1) | (g >> 1);
    const int idxA = (srcA * 16 + m) * 4;
    const int idxB = idxA ^ 64;
    const bool low = (lane < 32);
    const bool odd = (g & 1);
    const char* VcB0 = (const char*)Vc + m * 528;
    const char* VcB1 = (const char*)Vc + (16 + m) * 528;

    f32x4 oacc[8];
    #pragma unroll
    for (int nt = 0; nt < 8; ++nt) oacc[nt] = zero;

    const int qrow = w * 16 + m;

    #pragma unroll 1
    for (int h = 0; h < 4; ++h) {
        const char* wb = WBUF + (h & 1) * 43008;

        // ===== proj pass A: Q and K =====
        {
            f32x4 aq[2] = {zero, zero}, ak[2] = {zero, zero};
            #pragma unroll
            for (int kc = 0; kc < 4; ++kc) {
                short8 b0[2], b1[2];
                #pragma unroll
                for (int nt = 0; nt < 2; ++nt) {
                    int row = nt * 16 + m;
                    int off = (row * 256 + kc * 64 + 16 * g) ^ ((row & 7) << 4);
                    b0[nt] = *(const short8*)(wb + off);
                    b1[nt] = *(const short8*)(wb + 8192 + off);
                }
                __builtin_amdgcn_s_setprio(1);
                #pragma unroll
                for (int nt = 0; nt < 2; ++nt) {
                    aq[nt] = __builtin_amdgcn_mfma_f32_16x16x32_bf16(b0[nt], xa[kc], aq[nt], 0, 0, 0);
                    ak[nt] = __builtin_amdgcn_mfma_f32_16x16x32_bf16(b1[nt], xa[kc], ak[nt], 0, 0, 0);
                }
                __builtin_amdgcn_s_setprio(0);
            }
            #pragma unroll
            for (int nt = 0; nt < 2; ++nt) {
                int col = nt * 16 + 4 * g;
                ushort4 q4, k4;
                q4.x = f2bf(aq[nt][0]); q4.y = f2bf(aq[nt][1]);
                q4.z = f2bf(aq[nt][2]); q4.w = f2bf(aq[nt][3]);
                k4.x = f2bf(ak[nt][0]); k4.y = f2bf(ak[nt][1]);
                k4.z = f2bf(ak[nt][2]); k4.w = f2bf(ak[nt][3]);
                *(ushort4*)(Qg + qrow * 36 + col) = q4;
                *(ushort4*)(Kl + qrow * 36 + col) = k4;
            }
        }

        // ===== proj pass B: V (normal order -> vector col-major store) and
        //       G (swapped order, gate -> accumulator regs) =====
        f32x4 gacc[2];
        {
            f32x4 av4[2] = {zero, zero}, ag[2] = {zero, zero};
            #pragma unroll
            for (int kc = 0; kc < 4; ++kc) {
                short8 b0[2], b1[2];
                #pragma unroll
                for (int nt = 0; nt < 2; ++nt) {
                    int row = nt * 16 + m;
                    int off = (row * 256 + kc * 64 + 16 * g) ^ ((row & 7) << 4);
                    b0[nt] = *(const short8*)(wb + 16384 + off);
                    b1[nt] = *(const short8*)(wb + 24576 + off);
                }
                __builtin_amdgcn_s_setprio(1);
                #pragma unroll
                for (int nt = 0; nt < 2; ++nt) {
                    // V: NORMAL order -> lane (g,m) holds V[k=w*16+4g+r][d=nt*16+m]
                    av4[nt] = __builtin_amdgcn_mfma_f32_16x16x32_bf16(xa[kc], b0[nt], av4[nt], 0, 0, 0);
                    // G: swapped order (matches OG-store layout)
                    ag[nt]  = __builtin_amdgcn_mfma_f32_16x16x32_bf16(b1[nt], xa[kc], ag[nt], 0, 0, 0);
                }
                __builtin_amdgcn_s_setprio(0);
            }
            #pragma unroll
            for (int nt = 0; nt < 2; ++nt) {
                // Vc[d][k]: 4 consecutive k at fixed d -> one ushort4 store
                ushort4 v4;
                v4.x = f2bf(av4[nt][0]); v4.y = f2bf(av4[nt][1]);
                v4.z = f2bf(av4[nt][2]); v4.w = f2bf(av4[nt][3]);
                *(ushort4*)(Vc + (nt * 16 + m) * 264 + w * 16 + 4 * g) = v4;
                int col = nt * 16 + 4 * g;
                #pragma unroll
                for (int r = 0; r < 4; ++r)
                    gacc[nt][r] = 1.0f / (1.0f + __expf(-(ag[nt][r] + g_b[h * 32 + col + r])));
            }
        }
        __syncthreads();   // proj writes -> attn reads

        // ===== async stage of head h+1 (lands during attention) =====
        if (h < 3) {
            const char* src = wimg + (h + 1) * 43008 + w * 1024 + lane * 16;
            char* dst = WBUF + ((h + 1) & 1) * 43008 + w * 1024;
            load_lds16(src, dst);
            load_lds16(src + 16384, dst + 16384);
            if (w < 10) load_lds16(src + 32768, dst + 32768);
        }

        // ===== attention: this wave's q-tile =====
        const short8 qf = *(const short8*)((const char*)Qg + qrow * 72 + 16 * g);
        const float* triQ = triT + h * 65536 + w * 4096 + m * 16 + 4 * g;

        float ls = 0.f;
        f32x4 o0 = zero, o1 = zero;

        #pragma unroll
        for (int c = 0; c < 8; ++c) {
            int d00, d01, d10, d11;
            {
                const int kt = 2 * c;
                short8 af = *(const short8*)((const char*)Kl + (kt * 16 + m) * 72 + 16 * g);
                f32x4 bias = *(const f32x4*)(mb + kt * 16 + 4 * g)
                           + *(const f32x4*)(triQ + kt * 256);
                __builtin_amdgcn_s_setprio(1);
                f32x4 acc = __builtin_amdgcn_mfma_f32_16x16x32_bf16(af, qf, bias, 0, 0, 0);
                __builtin_amdgcn_s_setprio(0);
                float p0 = EXP2F(acc[0]);
                float p1 = EXP2F(acc[1]);
                float p2 = EXP2F(acc[2]);
                float p3 = EXP2F(acc[3]);
                ls += (p0 + p1) + (p2 + p3);
                d00 = pk2bf(p0, p1); d01 = pk2bf(p2, p3);
            }
            {
                const int kt = 2 * c + 1;
                short8 af = *(const short8*)((const char*)Kl + (kt * 16 + m) * 72 + 16 * g);
                f32x4 bias = *(const f32x4*)(mb + kt * 16 + 4 * g)
                           + *(const f32x4*)(triQ + kt * 256);
                __builtin_amdgcn_s_setprio(1);
                f32x4 acc = __builtin_amdgcn_mfma_f32_16x16x32_bf16(af, qf, bias, 0, 0, 0);
                __builtin_amdgcn_s_setprio(0);
                float p0 = EXP2F(acc[0]);
                float p1 = EXP2F(acc[1]);
                float p2 = EXP2F(acc[2]);
                float p3 = EXP2F(acc[3]);
                ls += (p0 + p1) + (p2 + p3);
                d10 = pk2bf(p0, p1); d11 = pk2bf(p2, p3);
            }
            // parity relabel (post-MFMA per-lane outputs: legal divergence)
            int pk0 = odd ? d10 : d00;
            int pk1 = odd ? d11 : d01;
            int pk2 = odd ? d00 : d10;
            int pk3 = odd ? d01 : d11;

            int dA0 = __builtin_amdgcn_ds_bpermute(idxA, pk0);
            int dA1 = __builtin_amdgcn_ds_bpermute(idxA, pk1);
            int dB0 = __builtin_amdgcn_ds_bpermute(idxB, pk2);
            int dB1 = __builtin_amdgcn_ds_bpermute(idxB, pk3);
            int4v bi;
            bi.x = low ? dA0 : dB0;
            bi.y = low ? dA1 : dB1;
            bi.z = low ? dB0 : dA0;
            bi.w = low ? dB1 : dA1;
            short8 bs = __builtin_bit_cast(short8, bi);

            short8 av0 = *(const short8*)(VcB0 + c * 64 + 16 * g);
            short8 av1 = *(const short8*)(VcB1 + c * 64 + 16 * g);
            __builtin_amdgcn_s_setprio(1);
            o0 = __builtin_amdgcn_mfma_f32_16x16x32_bf16(av0, bs, o0, 0, 0, 0);
            o1 = __builtin_amdgcn_mfma_f32_16x16x32_bf16(av1, bs, o1, 0, 0, 0);
            __builtin_amdgcn_s_setprio(0);
        }
        ls += __shfl_xor(ls, 16, 64);
        ls += __shfl_xor(ls, 32, 64);
        float inv = 1.0f / ls;

        ushort4 s0, s1;
        s0.x = f2bf(o0[0] * inv * gacc[0][0]);
        s0.y = f2bf(o0[1] * inv * gacc[0][1]);
        s0.z = f2bf(o0[2] * inv * gacc[0][2]);
        s0.w = f2bf(o0[3] * inv * gacc[0][3]);
        s1.x = f2bf(o1[0] * inv * gacc[1][0]);
        s1.y = f2bf(o1[1] * inv * gacc[1][1]);
        s1.z = f2bf(o1[2] * inv * gacc[1][2]);
        s1.w = f2bf(o1[3] * inv * gacc[1][3]);
        *(ushort4*)(Qg + qrow * 36 + 4 * g) = s0;           // OG over Q (own rows)
        *(ushort4*)(Qg + qrow * 36 + 16 + 4 * g) = s1;

        // ===== partial output projection (wave-local rows, no barrier) =====
        {
            short8 a = *(const short8*)((const char*)Qg + qrow * 72 + 16 * g);
            __builtin_amdgcn_s_setprio(1);
            #pragma unroll
            for (int nt = 0; nt < 8; ++nt) {
                short8 b = *(const short8*)(wb + 32768 + (nt * 16 + m) * 80 + 16 * g);
                oacc[nt] = __builtin_amdgcn_mfma_f32_16x16x32_bf16(b, a, oacc[nt], 0, 0, 0);
            }
            __builtin_amdgcn_s_setprio(0);
        }
        __syncthreads();   // drains prefetch vmcnt + all reads done before overwrite
    }

    // ===== epilogue: + o_b, fp32 store =====
    const int orow = i * 256 + qrow;
    #pragma unroll
    for (int nt = 0; nt < 8; ++nt) {
        int col = nt * 16 + 4 * g;
        float4 bv = *(const float4*)(o_b + col);
        float4 o;
        o.x = oacc[nt][0] + bv.x;
        o.y = oacc[nt][1] + bv.y;
        o.z = oacc[nt][2] + bv.z;
        o.w = oacc[nt][3] + bv.w;
        *(float4*)(out + (size_t)orow * 128 + col) = o;
    }
}

// ---------------------------------------------------------------------------
extern "C" void kernel_launch(void* const* d_in, const int* in_sizes, int n_in,
                              void* d_out, int out_size, void* d_ws, size_t ws_size,
                              hipStream_t stream) {
    (void)in_sizes; (void)n_in; (void)out_size; (void)ws_size;
    const float* x    = (const float*)d_in[0];
    const float* mask = (const float*)d_in[1];
    const float* ln_w = (const float*)d_in[2];
    const float* ln_b = (const float*)d_in[3];
    const float* tri_w= (const float*)d_in[4];
    const float* q_w  = (const float*)d_in[5];
    const float* k_w  = (const float*)d_in[6];
    const float* v_w  = (const float*)d_in[7];
    const float* g_w  = (const float*)d_in[8];
    const float* g_b  = (const float*)d_in[9];
    const float* o_w  = (const float*)d_in[10];
    const float* o_b  = (const float*)d_in[11];

    char* ws = (char*)d_ws;
    unsigned short* xn  = (unsigned short*)(ws);                 // 16 MB
    float*          tri = (float*)(ws + 16777216);               // 1 MB f32 tiled
    char*           wimg= (char*)(ws + 17825792);                // 168 KB images

    ln_prep_kernel<<<8234, 256, 0, stream>>>(x, ln_w, ln_b, tri_w,
                                             q_w, k_w, v_w, g_w, o_w,
                                             xn, tri, wimg);
    mega_kernel<<<256, 1024, 0, stream>>>(xn, wimg, g_b, mask, tri, o_b,
                                          (float*)d_out);
}